// Round 1
// baseline (222.164 us; speedup 1.0000x reference)
//
#include <hip/hip_runtime.h>

#define POOLED 7
#define SCALE 0.0625f

// antiderivative of unit hat: Phi(u), Phi(-inf)=0, matches reference _hat_cdf
__device__ __forceinline__ float hat_cdf(float u) {
  if (u <= 0.0f) {
    float t = fminf(fmaxf(u + 1.0f, 0.0f), 1.0f);
    return 0.5f * t * t;
  } else {
    float t = fminf(fmaxf(1.0f - u, 0.0f), 1.0f);
    return 1.0f - 0.5f * t * t;
  }
}

// [B][C][S] -> [B][S][C] tiled transpose (S = H*W), coalesced both sides
__global__ __launch_bounds__(256)
void transpose_kernel(const float* __restrict__ in, float* __restrict__ out,
                      int C, int S) {
  __shared__ float tile[32][33];
  int b  = blockIdx.z;
  int s0 = blockIdx.x * 32;
  int c0 = blockIdx.y * 32;
  const float* inb = in + (size_t)b * C * S;
  float* outb      = out + (size_t)b * S * C;
  int tx = threadIdx.x, ty = threadIdx.y;
#pragma unroll
  for (int j = 0; j < 4; j++) {
    int c = c0 + ty + j * 8;
    int s = s0 + tx;
    tile[ty + j * 8][tx] = (c < C && s < S) ? inb[(size_t)c * S + s] : 0.0f;
  }
  __syncthreads();
#pragma unroll
  for (int j = 0; j < 4; j++) {
    int s = s0 + ty + j * 8;
    int c = c0 + tx;
    if (s < S && c < C) outb[(size_t)s * C + c] = tile[tx][ty + j * 8];
  }
}

// TR=true: feat layout [B][H][W][C] (transposed scratch); TR=false: [B][C][H][W]
template <bool TR>
__global__ __launch_bounds__(256)
void prroi_kernel(const float* __restrict__ feat, const float* __restrict__ rois,
                  float* __restrict__ out, int N, int C, int H, int W) {
  const int PP = POOLED * POOLED;
  int blk = blockIdx.x;
  int n  = blk / PP;
  int pq = blk % PP;
  int p  = pq / POOLED;
  int q  = pq % POOLED;

  __shared__ float s_wy[48];
  __shared__ float s_wx[48];

  // uniform per-block roi geometry (broadcast loads)
  float bif = rois[n * 5 + 0];
  float x1  = rois[n * 5 + 1] * SCALE;
  float y1  = rois[n * 5 + 2] * SCALE;
  float x2  = rois[n * 5 + 3] * SCALE;
  float y2  = rois[n * 5 + 4] * SCALE;
  int bi = (int)bif;
  float bw = (x2 - x1) / (float)POOLED;
  float bh = (y2 - y1) / (float)POOLED;
  float xlo = x1 + q * bw, xhi = xlo + bw;
  float ylo = y1 + p * bh, yhi = ylo + bh;

  // index ranges where hat weights can be nonzero (widened by 1; zeros are harmless)
  int h0 = max(0, (int)floorf(ylo) - 1);
  int h1 = min(H - 1, (int)ceilf(yhi) + 1);
  int w0 = max(0, (int)floorf(xlo) - 1);
  int w1 = min(W - 1, (int)ceilf(xhi) + 1);
  int nh = h1 - h0 + 1;
  int nw = w1 - w0 + 1;
  if (nh > 48) nh = 48;  // cannot happen for this problem's extents; safety only
  if (nw > 48) nw = 48;

  for (int i = threadIdx.x; i < nh; i += blockDim.x) {
    float idx = (float)(h0 + i);
    s_wy[i] = hat_cdf(yhi - idx) - hat_cdf(ylo - idx);
  }
  for (int i = threadIdx.x; i < nw; i += blockDim.x) {
    float idx = (float)(w0 + i);
    s_wx[i] = hat_cdf(xhi - idx) - hat_cdf(xlo - idx);
  }
  __syncthreads();

  float area = fmaxf(bw * bh, 0.0f);
  float inv_area = (area > 0.0f) ? 1.0f / fmaxf(area, 1e-12f) : 0.0f;

  for (int c = threadIdx.x; c < C; c += blockDim.x) {
    float acc = 0.0f;
    for (int ih = 0; ih < nh; ih++) {
      float wyv = s_wy[ih];
      int h = h0 + ih;
      size_t base;
      if (TR) base = ((size_t)(bi * H + h) * W + w0) * C + c;
      else    base = ((size_t)(bi * C + c) * H + h) * W + w0;
      for (int iw = 0; iw < nw; iw++) {
        float f = TR ? feat[base + (size_t)iw * C] : feat[base + iw];
        acc += f * (wyv * s_wx[iw]);
      }
    }
    out[((size_t)n * C + c) * PP + pq] = acc * inv_area;
  }
}

extern "C" void kernel_launch(void* const* d_in, const int* in_sizes, int n_in,
                              void* d_out, int out_size, void* d_ws, size_t ws_size,
                              hipStream_t stream) {
  const float* feat = (const float*)d_in[0];
  const float* rois = (const float*)d_in[1];
  float* out = (float*)d_out;

  const int B = 2, H = 100, W = 100;
  int N = in_sizes[1] / 5;
  int C = out_size / (N * POOLED * POOLED);  // 256
  int S = H * W;

  size_t need = (size_t)B * C * S * sizeof(float);
  if (ws_size >= need) {
    float* ft = (float*)d_ws;
    dim3 tb(32, 8);
    dim3 tg((S + 31) / 32, (C + 31) / 32, B);
    transpose_kernel<<<tg, tb, 0, stream>>>(feat, ft, C, S);
    prroi_kernel<true><<<N * POOLED * POOLED, 256, 0, stream>>>(ft, rois, out, N, C, H, W);
  } else {
    prroi_kernel<false><<<N * POOLED * POOLED, 256, 0, stream>>>(feat, rois, out, N, C, H, W);
  }
}